// Round 1
// baseline (173.531 us; speedup 1.0000x reference)
//
#include <hip/hip_runtime.h>
#include <math.h>

// Problem constants
#define Bv 2
#define Tv 2048
#define Cv 1024
#define Hv 16
#define HDv 64
#define Mv (Bv * Tv)             // 4096 rows
#define SZv (Bv * Hv * Tv * HDv) // 4,194,304 elements per Q/K/V section

typedef short bf16x8 __attribute__((ext_vector_type(8)));
typedef float f32x4 __attribute__((ext_vector_type(4)));

static __device__ __forceinline__ unsigned short f2bf(float f) {
    unsigned u = __float_as_uint(f);
    u += 0x7fffu + ((u >> 16) & 1u);
    return (unsigned short)(u >> 16);
}

// Packed fp32x2 -> bf16x2 (RNE), single HW instr on gfx950.
static __device__ __forceinline__ unsigned f2bf2(float a, float b) {
    unsigned r;
    asm("v_cvt_pk_bf16_f32 %0, %1, %2" : "=v"(r) : "v"(a), "v"(b));
    return r;
}

#define AS1 __attribute__((address_space(1)))
#define AS3 __attribute__((address_space(3)))
// 16B-per-lane async global->LDS: LDS dest = wave-uniform base + lane*16.
#define GLD16(gp, lp) __builtin_amdgcn_global_load_lds( \
    (AS1 const void*)(const void*)(gp), (AS3 void*)(void*)(lp), 16, 0, 0)

#define WAITVM(n) asm volatile("s_waitcnt vmcnt(" #n ")" ::: "memory")
#define WAITLGKM0 asm volatile("s_waitcnt lgkmcnt(0)" ::: "memory")
#define BARRIER   asm volatile("s_barrier" ::: "memory")

// ---------------------------------------------------------------------------
// Prep: fused x fp32->bf16 convert + W_attn/W_proj transpose-to-bf16.
// Grid partition: [0,4096) cvt, [4096,7168) W_attn^T, [7168,8192) W_proj^T.
// ---------------------------------------------------------------------------
__global__ __launch_bounds__(256) void prep_kernel(
    const float* __restrict__ x, const float* __restrict__ Wa,
    const float* __restrict__ Wp,
    unsigned short* __restrict__ xB, unsigned short* __restrict__ WaT,
    unsigned short* __restrict__ WpT)
{
    __shared__ float tile[32][33];
    const int bid = blockIdx.x;
    const int tid = threadIdx.x;

    if (bid < 4096) {               // cvt x: 1,048,576 float4 groups
        int i = bid * 256 + tid;
        float4 f = ((const float4*)x)[i];
        ushort4 u;
        u.x = f2bf(f.x); u.y = f2bf(f.y); u.z = f2bf(f.z); u.w = f2bf(f.w);
        ((ushort4*)xB)[i] = u;
        return;
    }
    const float* src; unsigned short* dst; int Ncols, bi;
    if (bid < 7168) { bi = bid - 4096; Ncols = 3072; src = Wa; dst = WaT; }
    else            { bi = bid - 7168; Ncols = 1024; src = Wp; dst = WpT; }
    const int nct = Ncols / 32;
    const int c0 = (bi % nct) * 32, r0 = (bi / nct) * 32;
    const int tx = tid & 31, ty = tid >> 5;  // ty 0..7
    #pragma unroll
    for (int i = 0; i < 4; ++i)
        tile[ty + i * 8][tx] = src[(size_t)(r0 + ty + i * 8) * Ncols + c0 + tx];
    __syncthreads();
    #pragma unroll
    for (int i = 0; i < 4; ++i)
        dst[(size_t)(c0 + ty + i * 8) * Cv + r0 + tx] = f2bf(tile[tx][ty + i * 8]);
}

// ---------------------------------------------------------------------------
// Shared bf16 MFMA GEMM mainloop, K=1024, templated on A-tile height:
// AG=2 -> 128xN tile (identical to the proven 128x128 loop), AG=1 -> 64xN.
// Triple-buffered staging, one barrier per iter, prefetch distance 2,
// counted vmcnt (= GLDs per tile).  lds must hold 3*(2048*AG+4096) shorts.
// ---------------------------------------------------------------------------
template<int AG>
__device__ __forceinline__ void mm_mainloop_1024(
    const unsigned short* __restrict__ A, const unsigned short* __restrict__ Bt,
    unsigned short* lds, int rowBase, int colBase, f32x4 acc[][4])
{
    const int tid  = threadIdx.x;
    const int lane = tid & 63;
    const int w    = tid >> 6;
    const int quad = lane >> 4, l15 = lane & 15;
    const int wm = (w >> 1) * (32 * AG), wn = (w & 1) * 64;
    const int K = 1024;
    constexpr int ASZ = 2048 * AG;   // A-tile shorts per buffer
    constexpr int BUF = ASZ + 4096;  // shorts per buffer (A + 128x32 B)
    constexpr int MI  = 2 * AG;      // 16-row m-tiles per wave

    size_t offA[AG]; unsigned short* ldsA[AG];
    size_t offB[2];  unsigned short* ldsB[2];
    #pragma unroll
    for (int i = 0; i < AG; ++i) {
        int g = w * (64 * AG) + i * 64 + lane;
        int r = g >> 2, kc = (g & 3) ^ ((r >> 1) & 3);
        offA[i] = (size_t)(rowBase + r) * K + kc * 8;
        ldsA[i] = lds + (w * AG + i) * 512;
    }
    #pragma unroll
    for (int i = 0; i < 2; ++i) {
        int g = w * 128 + i * 64 + lane;
        int r = g >> 2, kc = (g & 3) ^ ((r >> 1) & 3);
        offB[i] = (size_t)(colBase + r) * K + kc * 8;
        ldsB[i] = lds + ASZ + (w * 2 + i) * 512;
    }

    const int sw = quad ^ ((l15 >> 1) & 3);
    int aoff[MI], boff[4];
    #pragma unroll
    for (int i = 0; i < MI; ++i) aoff[i] = ((wm + i * 16 + l15) * 4 + sw) * 8;
    #pragma unroll
    for (int i = 0; i < 4; ++i)  boff[i] = ASZ + ((wn + i * 16 + l15) * 4 + sw) * 8;

    // Prologue: tiles 0,1 into bufs 0,1.
    #pragma unroll
    for (int t = 0; t < 2; ++t) {
        #pragma unroll
        for (int i = 0; i < AG; ++i) GLD16(A + offA[i] + t * 32, ldsA[i] + t * BUF);
        #pragma unroll
        for (int i = 0; i < 2; ++i)  GLD16(Bt + offB[i] + t * 32, ldsB[i] + t * BUF);
    }

    int cur = 0;
    for (int i = 0; i < 32; ++i) {
        if (i < 31) {
            if constexpr (AG == 2) { WAITVM(4); } else { WAITVM(3); }
        } else { WAITVM(0); }
        BARRIER;
        if (i < 30) {
            int nb = cur + 2 * BUF; if (nb >= 3 * BUF) nb -= 3 * BUF;
            const int k2 = (i + 2) * 32;
            #pragma unroll
            for (int ai = 0; ai < AG; ++ai) GLD16(A + offA[ai] + k2, ldsA[ai] + nb);
            #pragma unroll
            for (int bi = 0; bi < 2; ++bi)  GLD16(Bt + offB[bi] + k2, ldsB[bi] + nb);
        }

        bf16x8 a[MI], b[4];
        #pragma unroll
        for (int j = 0; j < MI; ++j) a[j] = *(const bf16x8*)(lds + cur + aoff[j]);
        #pragma unroll
        for (int j = 0; j < 4; ++j)  b[j] = *(const bf16x8*)(lds + cur + boff[j]);

        #pragma unroll
        for (int mi = 0; mi < MI; ++mi)
            #pragma unroll
            for (int ni = 0; ni < 4; ++ni)
                acc[mi][ni] = __builtin_amdgcn_mfma_f32_16x16x32_bf16(
                    a[mi], b[ni], acc[mi][ni], 0, 0, 0);

        cur += BUF; if (cur == 3 * BUF) cur = 0;
    }
}

// ---------------------------------------------------------------------------
// QKV GEMM: bf16 MFMA; epilogue scatters Q,K [bh][t][d], V^T [bh][d][t].
// Q is pre-scaled by log2(e)/32 so attention's softmax is a bare exp2.
// ---------------------------------------------------------------------------
__global__ __launch_bounds__(256) void qkv_mm_kernel(
    const unsigned short* __restrict__ xB, const unsigned short* __restrict__ WaT,
    const float* __restrict__ bias,
    unsigned short* __restrict__ qB, unsigned short* __restrict__ kB,
    unsigned short* __restrict__ vT)
{
    __shared__ __align__(16) unsigned short lds[24576];
    const int rowBase = blockIdx.y * 128;
    const int colBase = blockIdx.x * 128;

    f32x4 acc[4][4];
    #pragma unroll
    for (int i = 0; i < 4; ++i)
        #pragma unroll
        for (int j = 0; j < 4; ++j) acc[i][j] = (f32x4){0.f, 0.f, 0.f, 0.f};

    mm_mainloop_1024<2>(xB, WaT, lds, rowBase, colBase, acc);
    __syncthreads();

    const int tid = threadIdx.x, lane = tid & 63, w = tid >> 6;
    const int quad = lane >> 4, l15 = lane & 15;
    const int wm = (w >> 1) * 64, wn = (w & 1) * 64;
    const int s = colBase / Cv;                       // 0=q,1=k,2=v (uniform)
    const int tloc = rowBase & (Tv - 1);
    const int bh0 = (rowBase / Tv) * Hv + (colBase % Cv) / HDv;

    if (s < 2) {
        const float qs = (s == 0) ? 0.04508422f : 1.0f;  // log2(e)/32
        #pragma unroll
        for (int mi = 0; mi < 4; ++mi)
            #pragma unroll
            for (int ni = 0; ni < 4; ++ni) {
                float bv = bias[colBase + wn + ni * 16 + l15];
                #pragma unroll
                for (int r = 0; r < 4; ++r) {
                    int m = wm + mi * 16 + quad * 4 + r;
                    int n = wn + ni * 16 + l15;
                    lds[m * 136 + n] = f2bf((acc[mi][ni][r] + bv) * qs);
                }
            }
        __syncthreads();
        unsigned short* dst = (s == 0) ? qB : kB;
        #pragma unroll
        for (int it = 0; it < 8; ++it) {
            int cc = tid + it * 256;
            int m = cc >> 4, j = cc & 15;
            uint4 v = *(const uint4*)(lds + m * 136 + j * 8);
            int hh = j >> 3, d0 = (j & 7) * 8;
            *(uint4*)(dst + ((size_t)(bh0 + hh) * Tv + tloc + m) * HDv + d0) = v;
        }
    } else {
        #pragma unroll
        for (int mi = 0; mi < 4; ++mi)
            #pragma unroll
            for (int ni = 0; ni < 4; ++ni) {
                float bv = bias[colBase + wn + ni * 16 + l15];
                #pragma unroll
                for (int r = 0; r < 4; ++r) {
                    int m = wm + mi * 16 + quad * 4 + r;
                    int n = wn + ni * 16 + l15;
                    lds[n * 136 + m] = f2bf(acc[mi][ni][r] + bv);
                }
            }
        __syncthreads();
        #pragma unroll
        for (int it = 0; it < 8; ++it) {
            int cc = tid + it * 256;
            int n = cc >> 4, j = cc & 15;
            uint4 v = *(const uint4*)(lds + n * 136 + j * 8);
            int hh = n >> 6, d = n & 63;
            *(uint4*)(vT + ((size_t)(bh0 + hh) * HDv + d) * Tv + tloc + j * 8) = v;
        }
    }
}

// ---------------------------------------------------------------------------
// Projection GEMM: 64x128 tiles -> grid 8x64 = 512 blocks = 2 blocks/CU
// (the 128x128 version had only 256 blocks = 1 block/CU: occupancy-starved,
// no cross-block overlap of the barrier/vmcnt drain).
// ---------------------------------------------------------------------------
__global__ __launch_bounds__(256) void proj_mm_kernel(
    const unsigned short* __restrict__ y0B, const unsigned short* __restrict__ WpT,
    const float* __restrict__ bias, float* __restrict__ out)
{
    __shared__ __align__(16) unsigned short lds[18432];  // 3 * (2048+4096) shorts
    const int rowBase = blockIdx.y * 64;
    const int colBase = blockIdx.x * 128;

    f32x4 acc[2][4];
    #pragma unroll
    for (int i = 0; i < 2; ++i)
        #pragma unroll
        for (int j = 0; j < 4; ++j) acc[i][j] = (f32x4){0.f, 0.f, 0.f, 0.f};

    mm_mainloop_1024<1>(y0B, WpT, lds, rowBase, colBase, acc);

    const int tid = threadIdx.x, lane = tid & 63, w = tid >> 6;
    const int quad = lane >> 4, l15 = lane & 15;
    const int wm = (w >> 1) * 32, wn = (w & 1) * 64;

    #pragma unroll
    for (int mi = 0; mi < 2; ++mi)
        #pragma unroll
        for (int ni = 0; ni < 4; ++ni) {
            int n = colBase + wn + ni * 16 + l15;
            float bv = bias[n];
            #pragma unroll
            for (int r = 0; r < 4; ++r) {
                int m = rowBase + wm + mi * 16 + quad * 4 + r;
                out[(size_t)m * Cv + n] = acc[mi][ni][r] + bv;
            }
        }
}

// ---------------------------------------------------------------------------
// Causal attention, R10: 32 q-rows/wave (2 rowgroups of 16) halves the K/V
// LDS re-read per FLOP (the measured bottleneck: 18 ds_read_b128 per 16-row
// wave-iter ~ 240 LDS-cyc vs 78 MFMA-cyc). Each block pairs q-tiles
// (j, 31-j): waves 0,1 own tile j, waves 2,3 own tile 31-j, sharing ONE
// staged K/V stream -> near-uniform work per block, grid 512 = exactly
// 2 blocks/CU all-resident, staging traffic x0.74. Cross-iteration P
// software pipeline kept from R9 (P(kt) written with NO wait; PV(kt-1) at
// the top of iter kt; lgkm in-order completion makes the cross-iter P
// dependency safe). Same-bh blocks share an XCD (bh = bid&31 -> bid%8
// fixed) so the 512 KB/head K/V stays L2-local.
// ---------------------------------------------------------------------------
__global__ __launch_bounds__(256, 2) void attn_kernel(
    const unsigned short* __restrict__ qB, const unsigned short* __restrict__ kB,
    const unsigned short* __restrict__ vT, unsigned short* __restrict__ y0B)
{
    // kv per buffer (8192 shorts): K tile [0,4096), V tile [4096,8192).
    __shared__ __align__(16) unsigned short kv[2 * 8192];       // 32 KB
    __shared__ __align__(16) unsigned short Pb[2][4][32 * 72];  // 36 KB (2 phases)

    const int tid  = threadIdx.x;
    const int lane = tid & 63;
    const int w    = tid >> 6;
    const int quad = lane >> 4;
    const int l15  = lane & 15;

    const int j  = blockIdx.x >> 5;          // paired-tile index 0..15
    const int bh = blockIdx.x & 31;
    const int qA = j, qBt = 31 - j;          // the two 64-row q-tiles
    const int tw = (w < 2) ? qA : qBt;       // this wave's q-tile
    const int ktmax = qBt;                   // k-tile stream length - 1
    const int qwbase = tw * 64 + (w & 1) * 32;

    // Q frags: 2 rowgroups x 2 d-halves, in registers.
    bf16x8 Qf[2][2];
    #pragma unroll
    for (int rg = 0; rg < 2; ++rg) {
        const unsigned short* qrow =
            qB + ((size_t)bh * Tv + qwbase + rg * 16 + l15) * HDv;
        Qf[rg][0] = *(const bf16x8*)(qrow + quad * 8);
        Qf[rg][1] = *(const bf16x8*)(qrow + 32 + quad * 8);
    }
    WAITVM(0);   // Q in regs; loop-local vmcnt tracks only staging GLDs

    f32x4 O[2][4];
    float l[2][4];
    #pragma unroll
    for (int rg = 0; rg < 2; ++rg)
        #pragma unroll
        for (int n = 0; n < 4; ++n) {
            O[rg][n] = (f32x4){0.f, 0.f, 0.f, 0.f};
            l[rg][n] = 0.f;
        }

    const unsigned short* Kbase = kB + (size_t)bh * Tv * HDv;
    const unsigned short* Vbase = vT + (size_t)bh * HDv * Tv;
    unsigned short* Pw0 = &Pb[0][w][0];
    unsigned short* Pw1 = &Pb[1][w][0];

    // Staging: thread covers 4 granule-slots/tile: K slots tid+{0,256},
    // V slots tid+{0,256}. Swizzles: K g^((row>>2)&7), V g^(d&7).
    const unsigned short* gK[2]; unsigned short* dK[2];
    const unsigned short* gV[2]; unsigned short* dV[2];
    #pragma unroll
    for (int i = 0; i < 2; ++i) {
        int slot = tid + i * 256;
        int row = slot >> 3;
        int gk = (slot & 7) ^ ((row >> 2) & 7);
        gK[i] = Kbase + row * HDv + gk * 8;
        dK[i] = kv + (size_t)(i * 256 + w * 64) * 8;
        int d = slot >> 3;
        int gv = (slot & 7) ^ (d & 7);
        gV[i] = Vbase + (size_t)d * Tv + gv * 8;
        dV[i] = kv + 4096 + (size_t)(i * 256 + w * 64) * 8;
    }

    // Fragment LDS short-offsets (constant across kt; add buffer offset).
    int koff[4][2], voff[4][2];
    #pragma unroll
    for (int ct = 0; ct < 4; ++ct) {
        int row = ct + 4 * l15;
        #pragma unroll
        for (int jj = 0; jj < 2; ++jj)
            koff[ct][jj] = (row * 8 + ((quad + 4 * jj) ^ (l15 & 7))) * 8;
    }
    #pragma unroll
    for (int nt = 0; nt < 4; ++nt) {
        int d = nt * 16 + l15;
        #pragma unroll
        for (int jj = 0; jj < 2; ++jj)
            voff[nt][jj] = 4096 + (d * 8 + ((quad + 4 * jj) ^ (l15 & 7))) * 8;
    }

    // Prologue: tile 0 into buf0.
    GLD16(gK[0], dK[0]);
    GLD16(gK[1], dK[1]);
    GLD16(gV[0], dV[0]);
    GLD16(gV[1], dV[1]);

    bf16x8 Vprev[4][2];
    int cur = 0;
    for (int kt = 0; kt <= ktmax; ++kt) {
        WAITVM(0);
        BARRIER;
        if (kt < ktmax) {
            const int kb1 = (kt + 1) * 64;
            const int nxt = 8192 - cur;
            GLD16(gK[0] + (size_t)kb1 * HDv, dK[0] + nxt);
            GLD16(gK[1] + (size_t)kb1 * HDv, dK[1] + nxt);
            GLD16(gV[0] + kb1, dV[0] + nxt);
            GLD16(gV[1] + kb1, dV[1] + nxt);
        }

        unsigned short* PwW = (kt & 1) ? Pw1 : Pw0;   // write phase (this tile)
        unsigned short* PwR = (kt & 1) ? Pw0 : Pw1;   // read phase (prev tile)

        // Deferred PV for tile kt-1 (P write latency hidden by one full iter)
        if (kt > 0 && kt - 1 <= tw) {
            #pragma unroll
            for (int rg = 0; rg < 2; ++rg) {
                const bf16x8 Pa0 = *(const bf16x8*)(PwR + (rg * 16 + l15) * 72 + quad * 8);
                const bf16x8 Pa1 = *(const bf16x8*)(PwR + (rg * 16 + l15) * 72 + 32 + quad * 8);
                #pragma unroll
                for (int nt = 0; nt < 4; ++nt) {
                    O[rg][nt] = __builtin_amdgcn_mfma_f32_16x16x32_bf16(Pa0, Vprev[nt][0], O[rg][nt], 0, 0, 0);
                    O[rg][nt] = __builtin_amdgcn_mfma_f32_16x16x32_bf16(Pa1, Vprev[nt][1], O[rg][nt], 0, 0, 0);
                }
            }
        }

        if (kt <= tw) {
            // K frags + S MFMA for tile kt (K frags shared by both rowgroups)
            bf16x8 Kb[4][2];
            #pragma unroll
            for (int ct = 0; ct < 4; ++ct) {
                Kb[ct][0] = *(const bf16x8*)(kv + cur + koff[ct][0]);
                Kb[ct][1] = *(const bf16x8*)(kv + cur + koff[ct][1]);
            }
            f32x4 S[2][4];
            #pragma unroll
            for (int rg = 0; rg < 2; ++rg)
                #pragma unroll
                for (int ct = 0; ct < 4; ++ct) {
                    S[rg][ct] = (f32x4){0.f, 0.f, 0.f, 0.f};
                    S[rg][ct] = __builtin_amdgcn_mfma_f32_16x16x32_bf16(Qf[rg][0], Kb[ct][0], S[rg][ct], 0, 0, 0);
                    S[rg][ct] = __builtin_amdgcn_mfma_f32_16x16x32_bf16(Qf[rg][1], Kb[ct][1], S[rg][ct], 0, 0, 0);
                }

            // V frags for tile kt (consumed by PV at iter kt+1 / epilogue)
            #pragma unroll
            for (int nt = 0; nt < 4; ++nt) {
                Vprev[nt][0] = *(const bf16x8*)(kv + cur + voff[nt][0]);
                Vprev[nt][1] = *(const bf16x8*)(kv + cur + voff[nt][1]);
            }

            if (kt == tw) {  // diagonal tile: mask key > q (tile-local coords)
                const int qloc = (w & 1) * 32;
                #pragma unroll
                for (int rg = 0; rg < 2; ++rg)
                    #pragma unroll
                    for (int ct = 0; ct < 4; ++ct)
                        #pragma unroll
                        for (int r = 0; r < 4; ++r)
                            if (ct + 4 * l15 > qloc + rg * 16 + quad * 4 + r)
                                S[rg][ct][r] = -1e30f;
            }

            #pragma unroll
            for (int rg = 0; rg < 2; ++rg) {
                float p[4][4];
                #pragma unroll
                for (int ct = 0; ct < 4; ++ct)
                    #pragma unroll
                    for (int r = 0; r < 4; ++r)
                        p[ct][r] = __builtin_amdgcn_exp2f(S[rg][ct][r]);
                #pragma unroll
                for (int r = 0; r < 4; ++r)
                    l[rg][r] += (p[0][r] + p[1][r]) + (p[2][r] + p[3][r]);

                // P pack into write phase; NO wait — read happens next iter.
                #pragma unroll
                for (int r = 0; r < 4; ++r) {
                    uint2 u = make_uint2(f2bf2(p[0][r], p[1][r]), f2bf2(p[2][r], p[3][r]));
                    *(uint2*)(PwW + (rg * 16 + quad * 4 + r) * 72 + l15 * 4) = u;
                }
            }
        }

        cur = 8192 - cur;
    }

    // Epilogue PV for the final staged tile — only waves whose q-tile IS the
    // last tile (waves 2,3; waves 0,1 finished their PV inside the loop).
    if (tw == ktmax) {
        unsigned short* PwR = (ktmax & 1) ? Pw1 : Pw0;
        #pragma unroll
        for (int rg = 0; rg < 2; ++rg) {
            const bf16x8 Pa0 = *(const bf16x8*)(PwR + (rg * 16 + l15) * 72 + quad * 8);
            const bf16x8 Pa1 = *(const bf16x8*)(PwR + (rg * 16 + l15) * 72 + 32 + quad * 8);
            #pragma unroll
            for (int nt = 0; nt < 4; ++nt) {
                O[rg][nt] = __builtin_amdgcn_mfma_f32_16x16x32_bf16(Pa0, Vprev[nt][0], O[rg][nt], 0, 0, 0);
                O[rg][nt] = __builtin_amdgcn_mfma_f32_16x16x32_bf16(Pa1, Vprev[nt][1], O[rg][nt], 0, 0, 0);
            }
        }
    }

    // One-time row-sum reduce across the 16 lanes holding each row's keys
    #pragma unroll
    for (int rg = 0; rg < 2; ++rg)
        #pragma unroll
        for (int r = 0; r < 4; ++r) {
            l[rg][r] += __shfl_xor(l[rg][r], 1);
            l[rg][r] += __shfl_xor(l[rg][r], 2);
            l[rg][r] += __shfl_xor(l[rg][r], 4);
            l[rg][r] += __shfl_xor(l[rg][r], 8);
        }

    const int b = bh >> 4, h = bh & 15;
    #pragma unroll
    for (int rg = 0; rg < 2; ++rg)
        #pragma unroll
        for (int r = 0; r < 4; ++r) {
            float inv = 1.f / l[rg][r];
            int q = qwbase + rg * 16 + quad * 4 + r;
            unsigned short* dst = y0B + ((size_t)(b * Tv + q)) * Cv + h * HDv + l15;
            #pragma unroll
            for (int n = 0; n < 4; ++n) dst[n * 16] = f2bf(O[rg][n][r] * inv);
        }
}

// ---------------------------------------------------------------------------
// Workspace: xB 8MB | WaT 6MB | WpT 2MB | qB,kB,vT 24MB | y0B 8MB (~48 MB).
// ---------------------------------------------------------------------------
extern "C" void kernel_launch(void* const* d_in, const int* in_sizes, int n_in,
                              void* d_out, int out_size, void* d_ws, size_t ws_size,
                              hipStream_t stream) {
    const float* x      = (const float*)d_in[0];
    const float* W_attn = (const float*)d_in[1];
    const float* b_attn = (const float*)d_in[2];
    const float* W_proj = (const float*)d_in[3];
    const float* b_proj = (const float*)d_in[4];
    float* out = (float*)d_out;

    unsigned short* xB  = (unsigned short*)d_ws;
    unsigned short* WaT = xB  + (size_t)Mv * Cv;
    unsigned short* WpT = WaT + (size_t)3 * Cv * Cv;
    unsigned short* qB  = WpT + (size_t)Cv * Cv;
    unsigned short* kB  = qB + (size_t)SZv;
    unsigned short* vT  = kB + (size_t)SZv;
    unsigned short* y0B = vT + (size_t)SZv;

    dim3 blk(256);
    prep_kernel<<<dim3(8192), blk, 0, stream>>>(x, W_attn, W_proj, xB, WaT, WpT);
    qkv_mm_kernel<<<dim3(3 * Cv / 128, Mv / 128), blk, 0, stream>>>(xB, WaT, b_attn, qB, kB, vT);
    attn_kernel<<<dim3(32 * 16), blk, 0, stream>>>(qB, kB, vT, y0B);
    proj_mm_kernel<<<dim3(Cv / 128, Mv / 64), blk, 0, stream>>>(y0B, WpT, b_proj, out);
}

// Round 3
// 164.726 us; speedup vs baseline: 1.0535x; 1.0535x over previous
//
#include <hip/hip_runtime.h>
#include <math.h>

// Problem constants
#define Bv 2
#define Tv 2048
#define Cv 1024
#define Hv 16
#define HDv 64
#define Mv (Bv * Tv)             // 4096 rows
#define SZv (Bv * Hv * Tv * HDv) // 4,194,304 elements per Q/K/V section

typedef short bf16x8 __attribute__((ext_vector_type(8)));
typedef float f32x4 __attribute__((ext_vector_type(4)));

static __device__ __forceinline__ unsigned short f2bf(float f) {
    unsigned u = __float_as_uint(f);
    u += 0x7fffu + ((u >> 16) & 1u);
    return (unsigned short)(u >> 16);
}

// Packed fp32x2 -> bf16x2 (RNE), single HW instr on gfx950.
static __device__ __forceinline__ unsigned f2bf2(float a, float b) {
    unsigned r;
    asm("v_cvt_pk_bf16_f32 %0, %1, %2" : "=v"(r) : "v"(a), "v"(b));
    return r;
}

#define AS1 __attribute__((address_space(1)))
#define AS3 __attribute__((address_space(3)))
// 16B-per-lane async global->LDS: LDS dest = wave-uniform base + lane*16.
#define GLD16(gp, lp) __builtin_amdgcn_global_load_lds( \
    (AS1 const void*)(const void*)(gp), (AS3 void*)(void*)(lp), 16, 0, 0)

#define WAITVM(n) asm volatile("s_waitcnt vmcnt(" #n ")" ::: "memory")
#define BARRIER   asm volatile("s_barrier" ::: "memory")

// ---------------------------------------------------------------------------
// Prep: fused x fp32->bf16 convert + W_attn/W_proj transpose-to-bf16.
// ---------------------------------------------------------------------------
__global__ __launch_bounds__(256) void prep_kernel(
    const float* __restrict__ x, const float* __restrict__ Wa,
    const float* __restrict__ Wp,
    unsigned short* __restrict__ xB, unsigned short* __restrict__ WaT,
    unsigned short* __restrict__ WpT)
{
    __shared__ float tile[32][33];
    const int bid = blockIdx.x;
    const int tid = threadIdx.x;

    if (bid < 4096) {               // cvt x: 1,048,576 float4 groups
        int i = bid * 256 + tid;
        float4 f = ((const float4*)x)[i];
        ushort4 u;
        u.x = f2bf(f.x); u.y = f2bf(f.y); u.z = f2bf(f.z); u.w = f2bf(f.w);
        ((ushort4*)xB)[i] = u;
        return;
    }
    const float* src; unsigned short* dst; int Ncols, bi;
    if (bid < 7168) { bi = bid - 4096; Ncols = 3072; src = Wa; dst = WaT; }
    else            { bi = bid - 7168; Ncols = 1024; src = Wp; dst = WpT; }
    const int nct = Ncols / 32;
    const int c0 = (bi % nct) * 32, r0 = (bi / nct) * 32;
    const int tx = tid & 31, ty = tid >> 5;  // ty 0..7
    #pragma unroll
    for (int i = 0; i < 4; ++i)
        tile[ty + i * 8][tx] = src[(size_t)(r0 + ty + i * 8) * Ncols + c0 + tx];
    __syncthreads();
    #pragma unroll
    for (int i = 0; i < 4; ++i)
        dst[(size_t)(c0 + ty + i * 8) * Cv + r0 + tx] = f2bf(tile[tx][ty + i * 8]);
}

// ---------------------------------------------------------------------------
// Shared bf16 MFMA GEMM mainloop, K=1024, templated on A-tile height:
// AG=2 -> 128xN tile, AG=1 -> 64xN. Triple-buffered staging, one barrier
// per iter, prefetch distance 2, counted vmcnt.
// ---------------------------------------------------------------------------
template<int AG>
__device__ __forceinline__ void mm_mainloop_1024(
    const unsigned short* __restrict__ A, const unsigned short* __restrict__ Bt,
    unsigned short* lds, int rowBase, int colBase, f32x4 acc[][4])
{
    const int tid  = threadIdx.x;
    const int lane = tid & 63;
    const int w    = tid >> 6;
    const int quad = lane >> 4, l15 = lane & 15;
    const int wm = (w >> 1) * (32 * AG), wn = (w & 1) * 64;
    const int K = 1024;
    constexpr int ASZ = 2048 * AG;   // A-tile shorts per buffer
    constexpr int BUF = ASZ + 4096;  // shorts per buffer (A + 128x32 B)
    constexpr int MI  = 2 * AG;      // 16-row m-tiles per wave

    size_t offA[AG]; unsigned short* ldsA[AG];
    size_t offB[2];  unsigned short* ldsB[2];
    #pragma unroll
    for (int i = 0; i < AG; ++i) {
        int g = w * (64 * AG) + i * 64 + lane;
        int r = g >> 2, kc = (g & 3) ^ ((r >> 1) & 3);
        offA[i] = (size_t)(rowBase + r) * K + kc * 8;
        ldsA[i] = lds + (w * AG + i) * 512;
    }
    #pragma unroll
    for (int i = 0; i < 2; ++i) {
        int g = w * 128 + i * 64 + lane;
        int r = g >> 2, kc = (g & 3) ^ ((r >> 1) & 3);
        offB[i] = (size_t)(colBase + r) * K + kc * 8;
        ldsB[i] = lds + ASZ + (w * 2 + i) * 512;
    }

    const int sw = quad ^ ((l15 >> 1) & 3);
    int aoff[MI], boff[4];
    #pragma unroll
    for (int i = 0; i < MI; ++i) aoff[i] = ((wm + i * 16 + l15) * 4 + sw) * 8;
    #pragma unroll
    for (int i = 0; i < 4; ++i)  boff[i] = ASZ + ((wn + i * 16 + l15) * 4 + sw) * 8;

    // Prologue: tiles 0,1 into bufs 0,1.
    #pragma unroll
    for (int t = 0; t < 2; ++t) {
        #pragma unroll
        for (int i = 0; i < AG; ++i) GLD16(A + offA[i] + t * 32, ldsA[i] + t * BUF);
        #pragma unroll
        for (int i = 0; i < 2; ++i)  GLD16(Bt + offB[i] + t * 32, ldsB[i] + t * BUF);
    }

    int cur = 0;
    for (int i = 0; i < 32; ++i) {
        if (i < 31) {
            if constexpr (AG == 2) { WAITVM(4); } else { WAITVM(3); }
        } else { WAITVM(0); }
        BARRIER;
        if (i < 30) {
            int nb = cur + 2 * BUF; if (nb >= 3 * BUF) nb -= 3 * BUF;
            const int k2 = (i + 2) * 32;
            #pragma unroll
            for (int ai = 0; ai < AG; ++ai) GLD16(A + offA[ai] + k2, ldsA[ai] + nb);
            #pragma unroll
            for (int bi = 0; bi < 2; ++bi)  GLD16(Bt + offB[bi] + k2, ldsB[bi] + nb);
        }

        bf16x8 a[MI], b[4];
        #pragma unroll
        for (int j = 0; j < MI; ++j) a[j] = *(const bf16x8*)(lds + cur + aoff[j]);
        #pragma unroll
        for (int j = 0; j < 4; ++j)  b[j] = *(const bf16x8*)(lds + cur + boff[j]);

        #pragma unroll
        for (int mi = 0; mi < MI; ++mi)
            #pragma unroll
            for (int ni = 0; ni < 4; ++ni)
                acc[mi][ni] = __builtin_amdgcn_mfma_f32_16x16x32_bf16(
                    a[mi], b[ni], acc[mi][ni], 0, 0, 0);

        cur += BUF; if (cur == 3 * BUF) cur = 0;
    }
}

// ---------------------------------------------------------------------------
// QKV GEMM. Epilogue scatters Q,K [bh][t][d]; V^T [bh][d][t'] where t' is
// key-permuted within each 32-key group so the attention kernel's
// in-register P fragments (lane holds its own q-row's 8 keys) line up with
// V's B-operand slots with NO cross-lane movement:
//   slot(key k): s0,s1 = k0,k1; s2 = k4; s3,s4 = k2,k3
//   (inverse: key(slot s) = 4*(s>>3) + (s&3) + 16*((s>>2)&1))
// Q is pre-scaled by log2(e)/32 so attention's softmax is a bare exp2.
// ---------------------------------------------------------------------------
__global__ __launch_bounds__(256) void qkv_mm_kernel(
    const unsigned short* __restrict__ xB, const unsigned short* __restrict__ WaT,
    const float* __restrict__ bias,
    unsigned short* __restrict__ qB, unsigned short* __restrict__ kB,
    unsigned short* __restrict__ vT)
{
    __shared__ __align__(16) unsigned short lds[24576];
    const int rowBase = blockIdx.y * 128;
    const int colBase = blockIdx.x * 128;

    f32x4 acc[4][4];
    #pragma unroll
    for (int i = 0; i < 4; ++i)
        #pragma unroll
        for (int j = 0; j < 4; ++j) acc[i][j] = (f32x4){0.f, 0.f, 0.f, 0.f};

    mm_mainloop_1024<2>(xB, WaT, lds, rowBase, colBase, acc);
    __syncthreads();

    const int tid = threadIdx.x, lane = tid & 63, w = tid >> 6;
    const int quad = lane >> 4, l15 = lane & 15;
    const int wm = (w >> 1) * 64, wn = (w & 1) * 64;
    const int s = colBase / Cv;                       // 0=q,1=k,2=v (uniform)
    const int tloc = rowBase & (Tv - 1);
    const int bh0 = (rowBase / Tv) * Hv + (colBase % Cv) / HDv;

    if (s < 2) {
        const float qs = (s == 0) ? 0.04508422f : 1.0f;  // log2(e)/32
        #pragma unroll
        for (int mi = 0; mi < 4; ++mi)
            #pragma unroll
            for (int ni = 0; ni < 4; ++ni) {
                float bv = bias[colBase + wn + ni * 16 + l15];
                #pragma unroll
                for (int r = 0; r < 4; ++r) {
                    int m = wm + mi * 16 + quad * 4 + r;
                    int n = wn + ni * 16 + l15;
                    lds[m * 136 + n] = f2bf((acc[mi][ni][r] + bv) * qs);
                }
            }
        __syncthreads();
        unsigned short* dst = (s == 0) ? qB : kB;
        #pragma unroll
        for (int it = 0; it < 8; ++it) {
            int cc = tid + it * 256;
            int m = cc >> 4, j = cc & 15;
            uint4 v = *(const uint4*)(lds + m * 136 + j * 8);
            int hh = j >> 3, d0 = (j & 7) * 8;
            *(uint4*)(dst + ((size_t)(bh0 + hh) * Tv + tloc + m) * HDv + d0) = v;
        }
    } else {
        #pragma unroll
        for (int mi = 0; mi < 4; ++mi)
            #pragma unroll
            for (int ni = 0; ni < 4; ++ni) {
                float bv = bias[colBase + wn + ni * 16 + l15];
                #pragma unroll
                for (int r = 0; r < 4; ++r) {
                    int m = wm + mi * 16 + quad * 4 + r;
                    int mk = m & 31;
                    int mp = (m & ~31) | (mk & 3) | (((mk >> 4) & 1) << 2)
                           | (((mk >> 2) & 3) << 3);
                    int n = wn + ni * 16 + l15;
                    lds[n * 136 + mp] = f2bf(acc[mi][ni][r] + bv);
                }
            }
        __syncthreads();
        #pragma unroll
        for (int it = 0; it < 8; ++it) {
            int cc = tid + it * 256;
            int n = cc >> 4, j = cc & 15;
            uint4 v = *(const uint4*)(lds + n * 136 + j * 8);
            int hh = n >> 6, d = n & 63;
            *(uint4*)(vT + ((size_t)(bh0 + hh) * HDv + d) * Tv + tloc + j * 8) = v;
        }
    }
}

// ---------------------------------------------------------------------------
// Projection GEMM: 64x128 tiles -> 512 blocks = 2 blocks/CU.
// ---------------------------------------------------------------------------
__global__ __launch_bounds__(256) void proj_mm_kernel(
    const unsigned short* __restrict__ y0B, const unsigned short* __restrict__ WpT,
    const float* __restrict__ bias, float* __restrict__ out)
{
    __shared__ __align__(16) unsigned short lds[18432];
    const int rowBase = blockIdx.y * 64;
    const int colBase = blockIdx.x * 128;

    f32x4 acc[2][4];
    #pragma unroll
    for (int i = 0; i < 2; ++i)
        #pragma unroll
        for (int j = 0; j < 4; ++j) acc[i][j] = (f32x4){0.f, 0.f, 0.f, 0.f};

    mm_mainloop_1024<1>(y0B, WpT, lds, rowBase, colBase, acc);

    const int tid = threadIdx.x, lane = tid & 63, w = tid >> 6;
    const int quad = lane >> 4, l15 = lane & 15;
    const int wm = (w >> 1) * 32, wn = (w & 1) * 64;

    #pragma unroll
    for (int mi = 0; mi < 2; ++mi)
        #pragma unroll
        for (int ni = 0; ni < 4; ++ni) {
            int n = colBase + wn + ni * 16 + l15;
            float bv = bias[n];
            #pragma unroll
            for (int r = 0; r < 4; ++r) {
                int m = rowBase + wm + mi * 16 + quad * 4 + r;
                out[(size_t)m * Cv + n] = acc[mi][ni][r] + bv;
            }
        }
}

// ---------------------------------------------------------------------------
// Causal attention, R12: P never touches LDS or crosses lanes. QK^T computed
// SWAPPED (mfma(K,Q) -> S^T: lane holds 8 scores for ONE q-row l15), softmax
// in registers, then 4x v_cvt_pk_bf16_f32 pack the PV A-operand directly —
// lane (quad,l15) owns exactly the 8 keys that fill its A slots quad*8+e,
// because vT's key order was pre-permuted (qkv epilogue) to
// key(slot s) = 4*(s>>3) + (s&3) + 16*((s>>2)&1). Block = 128-row q-tile,
// 4 waves x 32 rows, all waves active every iter. LDS = 48 KB triple-
// buffered K/V, prefetch distance 2, counted vmcnt(4), 3 blocks/CU.
// Heavy tiles dispatch first.
// ---------------------------------------------------------------------------
__global__ __launch_bounds__(256, 3) void attn_kernel(
    const unsigned short* __restrict__ qB, const unsigned short* __restrict__ kB,
    const unsigned short* __restrict__ vT, unsigned short* __restrict__ y0B)
{
    // Per buffer (8192 shorts): K tile [0,4096), V tile [4096,8192).
    __shared__ __align__(16) unsigned short kv[3 * 8192];   // 48 KB

    const int tid  = threadIdx.x;
    const int lane = tid & 63;
    const int w    = tid >> 6;
    const int quad = lane >> 4;
    const int l15  = lane & 15;

    const int qt = 15 - (blockIdx.x >> 5);   // q-tile (128 rows), heavy first
    const int bh = blockIdx.x & 31;
    const int ktmax = 2 * qt + 1;            // k-tiles are 64 keys
    const int ktw   = 2 * qt + (w >> 1);     // this wave's last compute tile
    const int qbase = qt * 128 + w * 32;

    // Q frags (B-operand: lane holds Q[qrow=l15][d quad*8+..]), 2 rowgroups.
    bf16x8 Qf[2][2];
    #pragma unroll
    for (int rg = 0; rg < 2; ++rg) {
        const unsigned short* qrow =
            qB + ((size_t)bh * Tv + qbase + rg * 16 + l15) * HDv;
        Qf[rg][0] = *(const bf16x8*)(qrow + quad * 8);
        Qf[rg][1] = *(const bf16x8*)(qrow + 32 + quad * 8);
    }
    WAITVM(0);   // Q in regs; loop-local vmcnt tracks only staging GLDs

    f32x4 O[2][4];
    float l[2] = {0.f, 0.f};
    #pragma unroll
    for (int rg = 0; rg < 2; ++rg)
        #pragma unroll
        for (int n = 0; n < 4; ++n) O[rg][n] = (f32x4){0.f, 0.f, 0.f, 0.f};

    const unsigned short* Kbase = kB + (size_t)bh * Tv * HDv;
    const unsigned short* Vbase = vT + (size_t)bh * HDv * Tv;

    // Staging: thread covers 4 granule-slots/tile (K 2, V 2).
    // K swizzle: granule pos = g ^ (row&7)  (A-operand read pattern).
    // V swizzle: granule pos = g ^ (d&7)    (B-operand read pattern).
    const unsigned short* gK[2]; unsigned short* dK[2];
    const unsigned short* gV[2]; unsigned short* dV[2];
    #pragma unroll
    for (int i = 0; i < 2; ++i) {
        int slot = tid + i * 256;
        int row = slot >> 3;
        int gk = (slot & 7) ^ (row & 7);
        gK[i] = Kbase + row * HDv + gk * 8;
        dK[i] = kv + (size_t)(i * 256 + w * 64) * 8;
        int d = slot >> 3;
        int gv = (slot & 7) ^ (d & 7);
        gV[i] = Vbase + (size_t)d * Tv + gv * 8;
        dV[i] = kv + 4096 + (size_t)(i * 256 + w * 64) * 8;
    }

    // Fragment LDS short-offsets (add buffer offset at use).
    // K A-operand: row = ct*16+l15, granule jj*4+quad, pos ^= (l15&7).
    int koff[4][2], voff[4][2];
    #pragma unroll
    for (int ct = 0; ct < 4; ++ct)
        #pragma unroll
        for (int jj = 0; jj < 2; ++jj)
            koff[ct][jj] = ((ct * 16 + l15) * 8 + ((jj * 4 + quad) ^ (l15 & 7))) * 8;
    #pragma unroll
    for (int nt = 0; nt < 4; ++nt)
        #pragma unroll
        for (int hh = 0; hh < 2; ++hh)
            voff[nt][hh] = 4096 + ((nt * 16 + l15) * 8 + ((quad + 4 * hh) ^ (l15 & 7))) * 8;

#define STAGE(t, bufoff) do { \
    GLD16(gK[0] + (size_t)(t) * 64 * HDv, dK[0] + (bufoff)); \
    GLD16(gK[1] + (size_t)(t) * 64 * HDv, dK[1] + (bufoff)); \
    GLD16(gV[0] + (t) * 64, dV[0] + (bufoff)); \
    GLD16(gV[1] + (t) * 64, dV[1] + (bufoff)); \
} while (0)

    // Prologue: tiles 0,1 into bufs 0,1 (ktmax >= 1 always).
    STAGE(0, 0);
    STAGE(1, 8192);

    int cur = 0;
    for (int kt = 0; kt <= ktmax; ++kt) {
        if (kt < ktmax) { WAITVM(4); } else { WAITVM(0); }
        BARRIER;
        if (kt + 2 <= ktmax) {
            int nb = cur + 16384; if (nb >= 24576) nb -= 24576;
            STAGE(kt + 2, nb);
        }

        if (kt <= ktw) {
            const unsigned short* kvc = kv + cur;
            #pragma unroll
            for (int hh = 0; hh < 2; ++hh) {          // key halves 0-31 / 32-63
                bf16x8 Kb[2][2];
                #pragma unroll
                for (int c2 = 0; c2 < 2; ++c2) {
                    int ct = hh * 2 + c2;
                    Kb[c2][0] = *(const bf16x8*)(kvc + koff[ct][0]);
                    Kb[c2][1] = *(const bf16x8*)(kvc + koff[ct][1]);
                }
                bf16x8 Vb[4];
                #pragma unroll
                for (int nt = 0; nt < 4; ++nt)
                    Vb[nt] = *(const bf16x8*)(kvc + voff[nt][hh]);

                f32x4 S[2][2];   // [rg][c2]: S^T, lane = (key quad*4+r, qrow l15)
                #pragma unroll
                for (int rg = 0; rg < 2; ++rg)
                    #pragma unroll
                    for (int c2 = 0; c2 < 2; ++c2) {
                        S[rg][c2] = (f32x4){0.f, 0.f, 0.f, 0.f};
                        S[rg][c2] = __builtin_amdgcn_mfma_f32_16x16x32_bf16(
                            Kb[c2][0], Qf[rg][0], S[rg][c2], 0, 0, 0);
                        S[rg][c2] = __builtin_amdgcn_mfma_f32_16x16x32_bf16(
                            Kb[c2][1], Qf[rg][1], S[rg][c2], 0, 0, 0);
                    }

                if (kt == ktw) {  // diagonal region: mask key > qrow (tile-local)
                    const int kb2 = (w >> 1) * 64 + hh * 32;
                    #pragma unroll
                    for (int rg = 0; rg < 2; ++rg) {
                        const int rrel = w * 32 + rg * 16 + l15;
                        #pragma unroll
                        for (int c2 = 0; c2 < 2; ++c2)
                            #pragma unroll
                            for (int r = 0; r < 4; ++r)
                                if (kb2 + c2 * 16 + quad * 4 + r > rrel)
                                    S[rg][c2][r] = -1e30f;
                    }
                }

                #pragma unroll
                for (int rg = 0; rg < 2; ++rg) {
                    float p0[4], p1[4];
                    #pragma unroll
                    for (int r = 0; r < 4; ++r) {
                        p0[r] = __builtin_amdgcn_exp2f(S[rg][0][r]);
                        p1[r] = __builtin_amdgcn_exp2f(S[rg][1][r]);
                    }
                    l[rg] += ((p0[0] + p0[1]) + (p0[2] + p0[3]))
                           + ((p1[0] + p1[1]) + (p1[2] + p1[3]));

                    // Direct pack: lane's 8 own-row P values ARE its A slots
                    // (keys quad*4+r at slots quad*8+r, 16+quad*4+r at +4).
                    union { unsigned u[4]; bf16x8 v; } pa;
                    pa.u[0] = f2bf2(p0[0], p0[1]);
                    pa.u[1] = f2bf2(p0[2], p0[3]);
                    pa.u[2] = f2bf2(p1[0], p1[1]);
                    pa.u[3] = f2bf2(p1[2], p1[3]);
                    #pragma unroll
                    for (int nt = 0; nt < 4; ++nt)
                        O[rg][nt] = __builtin_amdgcn_mfma_f32_16x16x32_bf16(
                            pa.v, Vb[nt], O[rg][nt], 0, 0, 0);
                }
            }
        }

        cur += 8192; if (cur == 24576) cur = 0;
    }
#undef STAGE

    // Row sums: lane (quad,l15) holds partials for qrow l15 -> reduce quads.
    #pragma unroll
    for (int rg = 0; rg < 2; ++rg) {
        l[rg] += __shfl_xor(l[rg], 16);
        l[rg] += __shfl_xor(l[rg], 32);
    }

    const int b = bh >> 4, h = bh & 15;
    #pragma unroll
    for (int rg = 0; rg < 2; ++rg)
        #pragma unroll
        for (int r = 0; r < 4; ++r) {
            // O row = quad*4+r; its rowsum lives at lane l15 = quad*4+r.
            float lr = __shfl(l[rg], quad * 4 + r);
            float inv = 1.f / lr;
            int q = qbase + rg * 16 + quad * 4 + r;
            unsigned short* dst = y0B + ((size_t)(b * Tv + q)) * Cv + h * HDv + l15;
            #pragma unroll
            for (int nt = 0; nt < 4; ++nt) dst[nt * 16] = f2bf(O[rg][nt][r] * inv);
        }
}

// ---------------------------------------------------------------------------
// Workspace: xB 8MB | WaT 6MB | WpT 2MB | qB,kB,vT 24MB | y0B 8MB (~48 MB).
// ---------------------------------------------------------------------------
extern "C" void kernel_launch(void* const* d_in, const int* in_sizes, int n_in,
                              void* d_out, int out_size, void* d_ws, size_t ws_size,
                              hipStream_t stream) {
    const float* x      = (const float*)d_in[0];
    const float* W_attn = (const float*)d_in[1];
    const float* b_attn = (const float*)d_in[2];
    const float* W_proj = (const float*)d_in[3];
    const float* b_proj = (const float*)d_in[4];
    float* out = (float*)d_out;

    unsigned short* xB  = (unsigned short*)d_ws;
    unsigned short* WaT = xB  + (size_t)Mv * Cv;
    unsigned short* WpT = WaT + (size_t)3 * Cv * Cv;
    unsigned short* qB  = WpT + (size_t)Cv * Cv;
    unsigned short* kB  = qB + (size_t)SZv;
    unsigned short* vT  = kB + (size_t)SZv;
    unsigned short* y0B = vT + (size_t)SZv;

    dim3 blk(256);
    prep_kernel<<<dim3(8192), blk, 0, stream>>>(x, W_attn, W_proj, xB, WaT, WpT);
    qkv_mm_kernel<<<dim3(3 * Cv / 128, Mv / 128), blk, 0, stream>>>(xB, WaT, b_attn, qB, kB, vT);
    attn_kernel<<<dim3(32 * 16), blk, 0, stream>>>(qB, kB, vT, y0B);
    proj_mm_kernel<<<dim3(Cv / 128, Mv / 64), blk, 0, stream>>>(y0B, WpT, b_proj, out);
}

// Round 6
// 163.041 us; speedup vs baseline: 1.0643x; 1.0103x over previous
//
#include <hip/hip_runtime.h>
#include <math.h>

// Problem constants
#define Bv 2
#define Tv 2048
#define Cv 1024
#define Hv 16
#define HDv 64
#define Mv (Bv * Tv)             // 4096 rows
#define SZv (Bv * Hv * Tv * HDv) // 4,194,304 elements per Q/K/V section

typedef short bf16x8 __attribute__((ext_vector_type(8)));
typedef float f32x4 __attribute__((ext_vector_type(4)));

static __device__ __forceinline__ unsigned short f2bf(float f) {
    unsigned u = __float_as_uint(f);
    u += 0x7fffu + ((u >> 16) & 1u);
    return (unsigned short)(u >> 16);
}

// Packed fp32x2 -> bf16x2 (RNE), single HW instr on gfx950.
static __device__ __forceinline__ unsigned f2bf2(float a, float b) {
    unsigned r;
    asm("v_cvt_pk_bf16_f32 %0, %1, %2" : "=v"(r) : "v"(a), "v"(b));
    return r;
}

#define AS1 __attribute__((address_space(1)))
#define AS3 __attribute__((address_space(3)))
// 16B-per-lane async global->LDS: LDS dest = wave-uniform base + lane*16.
#define GLD16(gp, lp) __builtin_amdgcn_global_load_lds( \
    (AS1 const void*)(const void*)(gp), (AS3 void*)(void*)(lp), 16, 0, 0)

#define WAITVM(n) asm volatile("s_waitcnt vmcnt(" #n ")" ::: "memory")
#define BARRIER   asm volatile("s_barrier" ::: "memory")

// ---------------------------------------------------------------------------
// Prep: fused x fp32->bf16 convert + W_attn/W_proj transpose-to-bf16.
// ---------------------------------------------------------------------------
__global__ __launch_bounds__(256) void prep_kernel(
    const float* __restrict__ x, const float* __restrict__ Wa,
    const float* __restrict__ Wp,
    unsigned short* __restrict__ xB, unsigned short* __restrict__ WaT,
    unsigned short* __restrict__ WpT)
{
    __shared__ float tile[32][33];
    const int bid = blockIdx.x;
    const int tid = threadIdx.x;

    if (bid < 4096) {               // cvt x: 1,048,576 float4 groups
        int i = bid * 256 + tid;
        float4 f = ((const float4*)x)[i];
        ushort4 u;
        u.x = f2bf(f.x); u.y = f2bf(f.y); u.z = f2bf(f.z); u.w = f2bf(f.w);
        ((ushort4*)xB)[i] = u;
        return;
    }
    const float* src; unsigned short* dst; int Ncols, bi;
    if (bid < 7168) { bi = bid - 4096; Ncols = 3072; src = Wa; dst = WaT; }
    else            { bi = bid - 7168; Ncols = 1024; src = Wp; dst = WpT; }
    const int nct = Ncols / 32;
    const int c0 = (bi % nct) * 32, r0 = (bi / nct) * 32;
    const int tx = tid & 31, ty = tid >> 5;  // ty 0..7
    #pragma unroll
    for (int i = 0; i < 4; ++i)
        tile[ty + i * 8][tx] = src[(size_t)(r0 + ty + i * 8) * Ncols + c0 + tx];
    __syncthreads();
    #pragma unroll
    for (int i = 0; i < 4; ++i)
        dst[(size_t)(c0 + ty + i * 8) * Cv + r0 + tx] = f2bf(tile[tx][ty + i * 8]);
}

// ---------------------------------------------------------------------------
// Shared bf16 MFMA GEMM mainloop, K=1024, templated on A-tile height:
// AG=2 -> 128xN tile, AG=1 -> 64xN. Triple-buffered staging, one barrier
// per iter, prefetch distance 2, counted vmcnt.
// ---------------------------------------------------------------------------
template<int AG>
__device__ __forceinline__ void mm_mainloop_1024(
    const unsigned short* __restrict__ A, const unsigned short* __restrict__ Bt,
    unsigned short* lds, int rowBase, int colBase, f32x4 acc[][4])
{
    const int tid  = threadIdx.x;
    const int lane = tid & 63;
    const int w    = tid >> 6;
    const int quad = lane >> 4, l15 = lane & 15;
    const int wm = (w >> 1) * (32 * AG), wn = (w & 1) * 64;
    const int K = 1024;
    constexpr int ASZ = 2048 * AG;   // A-tile shorts per buffer
    constexpr int BUF = ASZ + 4096;  // shorts per buffer (A + 128x32 B)
    constexpr int MI  = 2 * AG;      // 16-row m-tiles per wave

    size_t offA[AG]; unsigned short* ldsA[AG];
    size_t offB[2];  unsigned short* ldsB[2];
    #pragma unroll
    for (int i = 0; i < AG; ++i) {
        int g = w * (64 * AG) + i * 64 + lane;
        int r = g >> 2, kc = (g & 3) ^ ((r >> 1) & 3);
        offA[i] = (size_t)(rowBase + r) * K + kc * 8;
        ldsA[i] = lds + (w * AG + i) * 512;
    }
    #pragma unroll
    for (int i = 0; i < 2; ++i) {
        int g = w * 128 + i * 64 + lane;
        int r = g >> 2, kc = (g & 3) ^ ((r >> 1) & 3);
        offB[i] = (size_t)(colBase + r) * K + kc * 8;
        ldsB[i] = lds + ASZ + (w * 2 + i) * 512;
    }

    const int sw = quad ^ ((l15 >> 1) & 3);
    int aoff[MI], boff[4];
    #pragma unroll
    for (int i = 0; i < MI; ++i) aoff[i] = ((wm + i * 16 + l15) * 4 + sw) * 8;
    #pragma unroll
    for (int i = 0; i < 4; ++i)  boff[i] = ASZ + ((wn + i * 16 + l15) * 4 + sw) * 8;

    // Prologue: tiles 0,1 into bufs 0,1.
    #pragma unroll
    for (int t = 0; t < 2; ++t) {
        #pragma unroll
        for (int i = 0; i < AG; ++i) GLD16(A + offA[i] + t * 32, ldsA[i] + t * BUF);
        #pragma unroll
        for (int i = 0; i < 2; ++i)  GLD16(Bt + offB[i] + t * 32, ldsB[i] + t * BUF);
    }

    int cur = 0;
    for (int i = 0; i < 32; ++i) {
        if (i < 31) {
            if constexpr (AG == 2) { WAITVM(4); } else { WAITVM(3); }
        } else { WAITVM(0); }
        BARRIER;
        if (i < 30) {
            int nb = cur + 2 * BUF; if (nb >= 3 * BUF) nb -= 3 * BUF;
            const int k2 = (i + 2) * 32;
            #pragma unroll
            for (int ai = 0; ai < AG; ++ai) GLD16(A + offA[ai] + k2, ldsA[ai] + nb);
            #pragma unroll
            for (int bi = 0; bi < 2; ++bi)  GLD16(Bt + offB[bi] + k2, ldsB[bi] + nb);
        }

        bf16x8 a[MI], b[4];
        #pragma unroll
        for (int j = 0; j < MI; ++j) a[j] = *(const bf16x8*)(lds + cur + aoff[j]);
        #pragma unroll
        for (int j = 0; j < 4; ++j)  b[j] = *(const bf16x8*)(lds + cur + boff[j]);

        #pragma unroll
        for (int mi = 0; mi < MI; ++mi)
            #pragma unroll
            for (int ni = 0; ni < 4; ++ni)
                acc[mi][ni] = __builtin_amdgcn_mfma_f32_16x16x32_bf16(
                    a[mi], b[ni], acc[mi][ni], 0, 0, 0);

        cur += BUF; if (cur == 3 * BUF) cur = 0;
    }
}

// ---------------------------------------------------------------------------
// QKV GEMM. Epilogue scatters Q,K [bh][t][d]; V^T [bh][d][t'] where t' is
// key-permuted within each 32-key group so the attention kernel's
// in-register P fragments (lane holds its own q-row's 8 keys) line up with
// V's B-operand slots with NO cross-lane movement:
//   (inverse: key(slot s) = 4*(s>>3) + (s&3) + 16*((s>>2)&1))
// Q is pre-scaled by log2(e)/32 so attention's softmax is a bare exp2.
// ---------------------------------------------------------------------------
__global__ __launch_bounds__(256) void qkv_mm_kernel(
    const unsigned short* __restrict__ xB, const unsigned short* __restrict__ WaT,
    const float* __restrict__ bias,
    unsigned short* __restrict__ qB, unsigned short* __restrict__ kB,
    unsigned short* __restrict__ vT)
{
    __shared__ __align__(16) unsigned short lds[24576];
    const int rowBase = blockIdx.y * 128;
    const int colBase = blockIdx.x * 128;

    f32x4 acc[4][4];
    #pragma unroll
    for (int i = 0; i < 4; ++i)
        #pragma unroll
        for (int j = 0; j < 4; ++j) acc[i][j] = (f32x4){0.f, 0.f, 0.f, 0.f};

    mm_mainloop_1024<2>(xB, WaT, lds, rowBase, colBase, acc);
    __syncthreads();

    const int tid = threadIdx.x, lane = tid & 63, w = tid >> 6;
    const int quad = lane >> 4, l15 = lane & 15;
    const int wm = (w >> 1) * 64, wn = (w & 1) * 64;
    const int s = colBase / Cv;                       // 0=q,1=k,2=v (uniform)
    const int tloc = rowBase & (Tv - 1);
    const int bh0 = (rowBase / Tv) * Hv + (colBase % Cv) / HDv;

    if (s < 2) {
        const float qs = (s == 0) ? 0.04508422f : 1.0f;  // log2(e)/32
        #pragma unroll
        for (int mi = 0; mi < 4; ++mi)
            #pragma unroll
            for (int ni = 0; ni < 4; ++ni) {
                float bv = bias[colBase + wn + ni * 16 + l15];
                #pragma unroll
                for (int r = 0; r < 4; ++r) {
                    int m = wm + mi * 16 + quad * 4 + r;
                    int n = wn + ni * 16 + l15;
                    lds[m * 136 + n] = f2bf((acc[mi][ni][r] + bv) * qs);
                }
            }
        __syncthreads();
        unsigned short* dst = (s == 0) ? qB : kB;
        #pragma unroll
        for (int it = 0; it < 8; ++it) {
            int cc = tid + it * 256;
            int m = cc >> 4, j = cc & 15;
            uint4 v = *(const uint4*)(lds + m * 136 + j * 8);
            int hh = j >> 3, d0 = (j & 7) * 8;
            *(uint4*)(dst + ((size_t)(bh0 + hh) * Tv + tloc + m) * HDv + d0) = v;
        }
    } else {
        #pragma unroll
        for (int mi = 0; mi < 4; ++mi)
            #pragma unroll
            for (int ni = 0; ni < 4; ++ni) {
                float bv = bias[colBase + wn + ni * 16 + l15];
                #pragma unroll
                for (int r = 0; r < 4; ++r) {
                    int m = wm + mi * 16 + quad * 4 + r;
                    int mk = m & 31;
                    int mp = (m & ~31) | (mk & 3) | (((mk >> 4) & 1) << 2)
                           | (((mk >> 2) & 3) << 3);
                    int n = wn + ni * 16 + l15;
                    lds[n * 136 + mp] = f2bf(acc[mi][ni][r] + bv);
                }
            }
        __syncthreads();
        #pragma unroll
        for (int it = 0; it < 8; ++it) {
            int cc = tid + it * 256;
            int n = cc >> 4, j = cc & 15;
            uint4 v = *(const uint4*)(lds + n * 136 + j * 8);
            int hh = n >> 6, d = n & 63;
            *(uint4*)(vT + ((size_t)(bh0 + hh) * HDv + d) * Tv + tloc + j * 8) = v;
        }
    }
}

// ---------------------------------------------------------------------------
// Projection GEMM: 64x128 tiles -> 512 blocks = 2 blocks/CU.
// ---------------------------------------------------------------------------
__global__ __launch_bounds__(256) void proj_mm_kernel(
    const unsigned short* __restrict__ y0B, const unsigned short* __restrict__ WpT,
    const float* __restrict__ bias, float* __restrict__ out)
{
    __shared__ __align__(16) unsigned short lds[18432];
    const int rowBase = blockIdx.y * 64;
    const int colBase = blockIdx.x * 128;

    f32x4 acc[2][4];
    #pragma unroll
    for (int i = 0; i < 2; ++i)
        #pragma unroll
        for (int j = 0; j < 4; ++j) acc[i][j] = (f32x4){0.f, 0.f, 0.f, 0.f};

    mm_mainloop_1024<1>(y0B, WpT, lds, rowBase, colBase, acc);

    const int tid = threadIdx.x, lane = tid & 63, w = tid >> 6;
    const int quad = lane >> 4, l15 = lane & 15;
    const int wm = (w >> 1) * 32, wn = (w & 1) * 64;

    #pragma unroll
    for (int mi = 0; mi < 2; ++mi)
        #pragma unroll
        for (int ni = 0; ni < 4; ++ni) {
            int n = colBase + wn + ni * 16 + l15;
            float bv = bias[n];
            #pragma unroll
            for (int r = 0; r < 4; ++r) {
                int m = rowBase + wm + mi * 16 + quad * 4 + r;
                out[(size_t)m * Cv + n] = acc[mi][ni][r] + bv;
            }
        }
}

// ---------------------------------------------------------------------------
// Causal attention, R15 = R12 (verified) + ONE change: balanced qt decode.
// Round-robin dispatch puts blocks i and i+256 on the same CU slot; decode
// qt so those pair to qt + (15-qt) = 15 -> every CU gets a uniform 34
// iteration-units (was 20..48, wall set by 48). The decode is a pure
// bijection over (qt,bh); blocks only read shared K/V and write disjoint
// y0B rows, so it cannot affect correctness.
// NOTE: s_setprio is BANNED here — present in both R13 and R14 (NaN),
// absent in R12 (pass). Suspected hipcc scheduling interaction with the
// inline-asm cvt_pk + union type-pun feeding the PV MFMA.
// ---------------------------------------------------------------------------
__global__ __launch_bounds__(256, 3) void attn_kernel(
    const unsigned short* __restrict__ qB, const unsigned short* __restrict__ kB,
    const unsigned short* __restrict__ vT, unsigned short* __restrict__ y0B)
{
    // Per buffer (8192 shorts): K tile [0,4096), V tile [4096,8192).
    __shared__ __align__(16) unsigned short kv[3 * 8192];   // 48 KB

    const int tid  = threadIdx.x;
    const int lane = tid & 63;
    const int w    = tid >> 6;
    const int quad = lane >> 4;
    const int l15  = lane & 15;

    // Balanced decode: block i (i<256) -> qt 15-(i>>5); block i+256 -> i>>5.
    const int bid = blockIdx.x;
    const int idx = bid & 255;
    const int qt  = (bid & 256) ? (idx >> 5) : (15 - (idx >> 5));
    const int bh  = idx & 31;

    const int ktmax = 2 * qt + 1;            // k-tiles are 64 keys
    const int ktw   = 2 * qt + (w >> 1);     // this wave's last compute tile
    const int qbase = qt * 128 + w * 32;

    // Q frags (B-operand: lane holds Q[qrow=l15][d quad*8+..]), 2 rowgroups.
    bf16x8 Qf[2][2];
    #pragma unroll
    for (int rg = 0; rg < 2; ++rg) {
        const unsigned short* qrow =
            qB + ((size_t)bh * Tv + qbase + rg * 16 + l15) * HDv;
        Qf[rg][0] = *(const bf16x8*)(qrow + quad * 8);
        Qf[rg][1] = *(const bf16x8*)(qrow + 32 + quad * 8);
    }
    WAITVM(0);   // Q in regs; loop-local vmcnt tracks only staging GLDs

    f32x4 O[2][4];
    float l[2] = {0.f, 0.f};
    #pragma unroll
    for (int rg = 0; rg < 2; ++rg)
        #pragma unroll
        for (int n = 0; n < 4; ++n) O[rg][n] = (f32x4){0.f, 0.f, 0.f, 0.f};

    const unsigned short* Kbase = kB + (size_t)bh * Tv * HDv;
    const unsigned short* Vbase = vT + (size_t)bh * HDv * Tv;

    // Staging: thread covers 4 granule-slots/tile (K 2, V 2).
    // K swizzle: granule pos = g ^ (row&7)  (A-operand read pattern).
    // V swizzle: granule pos = g ^ (d&7)    (B-operand read pattern).
    const unsigned short* gK[2]; unsigned short* dK[2];
    const unsigned short* gV[2]; unsigned short* dV[2];
    #pragma unroll
    for (int i = 0; i < 2; ++i) {
        int slot = tid + i * 256;
        int row = slot >> 3;
        int gk = (slot & 7) ^ (row & 7);
        gK[i] = Kbase + row * HDv + gk * 8;
        dK[i] = kv + (size_t)(i * 256 + w * 64) * 8;
        int d = slot >> 3;
        int gv = (slot & 7) ^ (d & 7);
        gV[i] = Vbase + (size_t)d * Tv + gv * 8;
        dV[i] = kv + 4096 + (size_t)(i * 256 + w * 64) * 8;
    }

    // Fragment LDS short-offsets (add buffer offset at use).
    int koff[4][2], voff[4][2];
    #pragma unroll
    for (int ct = 0; ct < 4; ++ct)
        #pragma unroll
        for (int jj = 0; jj < 2; ++jj)
            koff[ct][jj] = ((ct * 16 + l15) * 8 + ((jj * 4 + quad) ^ (l15 & 7))) * 8;
    #pragma unroll
    for (int nt = 0; nt < 4; ++nt)
        #pragma unroll
        for (int hh = 0; hh < 2; ++hh)
            voff[nt][hh] = 4096 + ((nt * 16 + l15) * 8 + ((quad + 4 * hh) ^ (l15 & 7))) * 8;

#define STAGE(t, bufoff) do { \
    GLD16(gK[0] + (size_t)(t) * 64 * HDv, dK[0] + (bufoff)); \
    GLD16(gK[1] + (size_t)(t) * 64 * HDv, dK[1] + (bufoff)); \
    GLD16(gV[0] + (t) * 64, dV[0] + (bufoff)); \
    GLD16(gV[1] + (t) * 64, dV[1] + (bufoff)); \
} while (0)

    // Prologue: tiles 0,1 into bufs 0,1 (ktmax >= 1 always).
    STAGE(0, 0);
    STAGE(1, 8192);

    int cur = 0;
    for (int kt = 0; kt <= ktmax; ++kt) {
        if (kt < ktmax) { WAITVM(4); } else { WAITVM(0); }
        BARRIER;
        if (kt + 2 <= ktmax) {
            int nb = cur + 16384; if (nb >= 24576) nb -= 24576;
            STAGE(kt + 2, nb);
        }

        if (kt <= ktw) {
            const unsigned short* kvc = kv + cur;
            #pragma unroll
            for (int hh = 0; hh < 2; ++hh) {          // key halves 0-31 / 32-63
                bf16x8 Kb[2][2];
                #pragma unroll
                for (int c2 = 0; c2 < 2; ++c2) {
                    int ct = hh * 2 + c2;
                    Kb[c2][0] = *(const bf16x8*)(kvc + koff[ct][0]);
                    Kb[c2][1] = *(const bf16x8*)(kvc + koff[ct][1]);
                }
                bf16x8 Vb[4];
                #pragma unroll
                for (int nt = 0; nt < 4; ++nt)
                    Vb[nt] = *(const bf16x8*)(kvc + voff[nt][hh]);

                f32x4 S[2][2];   // [rg][c2]: S^T, lane = (key quad*4+r, qrow l15)
                #pragma unroll
                for (int rg = 0; rg < 2; ++rg)
                    #pragma unroll
                    for (int c2 = 0; c2 < 2; ++c2) {
                        S[rg][c2] = (f32x4){0.f, 0.f, 0.f, 0.f};
                        S[rg][c2] = __builtin_amdgcn_mfma_f32_16x16x32_bf16(
                            Kb[c2][0], Qf[rg][0], S[rg][c2], 0, 0, 0);
                        S[rg][c2] = __builtin_amdgcn_mfma_f32_16x16x32_bf16(
                            Kb[c2][1], Qf[rg][1], S[rg][c2], 0, 0, 0);
                    }

                if (kt == ktw) {  // diagonal region: mask key > qrow (tile-local)
                    const int kb2 = (w >> 1) * 64 + hh * 32;
                    #pragma unroll
                    for (int rg = 0; rg < 2; ++rg) {
                        const int rrel = w * 32 + rg * 16 + l15;
                        #pragma unroll
                        for (int c2 = 0; c2 < 2; ++c2)
                            #pragma unroll
                            for (int r = 0; r < 4; ++r)
                                if (kb2 + c2 * 16 + quad * 4 + r > rrel)
                                    S[rg][c2][r] = -1e30f;
                    }
                }

                #pragma unroll
                for (int rg = 0; rg < 2; ++rg) {
                    float p0[4], p1[4];
                    #pragma unroll
                    for (int r = 0; r < 4; ++r) {
                        p0[r] = __builtin_amdgcn_exp2f(S[rg][0][r]);
                        p1[r] = __builtin_amdgcn_exp2f(S[rg][1][r]);
                    }
                    l[rg] += ((p0[0] + p0[1]) + (p0[2] + p0[3]))
                           + ((p1[0] + p1[1]) + (p1[2] + p1[3]));

                    // Direct pack: lane's 8 own-row P values ARE its A slots
                    // (keys quad*4+r at slots quad*8+r, 16+quad*4+r at +4).
                    union { unsigned u[4]; bf16x8 v; } pa;
                    pa.u[0] = f2bf2(p0[0], p0[1]);
                    pa.u[1] = f2bf2(p0[2], p0[3]);
                    pa.u[2] = f2bf2(p1[0], p1[1]);
                    pa.u[3] = f2bf2(p1[2], p1[3]);
                    #pragma unroll
                    for (int nt = 0; nt < 4; ++nt)
                        O[rg][nt] = __builtin_amdgcn_mfma_f32_16x16x32_bf16(
                            pa.v, Vb[nt], O[rg][nt], 0, 0, 0);
                }
            }
        }

        cur += 8192; if (cur == 24576) cur = 0;
    }
#undef STAGE

    // Row sums: lane (quad,l15) holds partials for qrow l15 -> reduce quads.
    #pragma unroll
    for (int rg = 0; rg < 2; ++rg) {
        l[rg] += __shfl_xor(l[rg], 16);
        l[rg] += __shfl_xor(l[rg], 32);
    }

    const int b = bh >> 4, h = bh & 15;
    #pragma unroll
    for (int rg = 0; rg < 2; ++rg)
        #pragma unroll
        for (int r = 0; r < 4; ++r) {
            // O row = quad*4+r; its rowsum lives at lane l15 = quad*4+r.
            float lr = __shfl(l[rg], quad * 4 + r);
            float inv = 1.f / lr;
            int q = qbase + rg * 16 + quad * 4 + r;
            unsigned short* dst = y0B + ((size_t)(b * Tv + q)) * Cv + h * HDv + l15;
            #pragma unroll
            for (int nt = 0; nt < 4; ++nt) dst[nt * 16] = f2bf(O[rg][nt][r] * inv);
        }
}

// ---------------------------------------------------------------------------
// Workspace: xB 8MB | WaT 6MB | WpT 2MB | qB,kB,vT 24MB | y0B 8MB (~48 MB).
// ---------------------------------------------------------------------------
extern "C" void kernel_launch(void* const* d_in, const int* in_sizes, int n_in,
                              void* d_out, int out_size, void* d_ws, size_t ws_size,
                              hipStream_t stream) {
    const float* x      = (const float*)d_in[0];
    const float* W_attn = (const float*)d_in[1];
    const float* b_attn = (const float*)d_in[2];
    const float* W_proj = (const float*)d_in[3];
    const float* b_proj = (const float*)d_in[4];
    float* out = (float*)d_out;

    unsigned short* xB  = (unsigned short*)d_ws;
    unsigned short* WaT = xB  + (size_t)Mv * Cv;
    unsigned short* WpT = WaT + (size_t)3 * Cv * Cv;
    unsigned short* qB  = WpT + (size_t)Cv * Cv;
    unsigned short* kB  = qB + (size_t)SZv;
    unsigned short* vT  = kB + (size_t)SZv;
    unsigned short* y0B = vT + (size_t)SZv;

    dim3 blk(256);
    prep_kernel<<<dim3(8192), blk, 0, stream>>>(x, W_attn, W_proj, xB, WaT, WpT);
    qkv_mm_kernel<<<dim3(3 * Cv / 128, Mv / 128), blk, 0, stream>>>(xB, WaT, b_attn, qB, kB, vT);
    attn_kernel<<<dim3(32 * 16), blk, 0, stream>>>(qB, kB, vT, y0B);
    proj_mm_kernel<<<dim3(Cv / 128, Mv / 64), blk, 0, stream>>>(y0B, WpT, b_proj, out);
}